// Round 1
// baseline (124.896 us; speedup 1.0000x reference)
//
#include <hip/hip_runtime.h>
#include <hip/hip_bf16.h>

#define NF 200
#define ND 32
#define NK 4
#define NH1 32
#define NH2 16
#define BN_EPS 1e-3f

// One wave (64 lanes) per batch row. Lane = fg*8 + dl:
//   fg in [0,8): which of 8 f-rows this lane helps with per iteration
//   dl in [0,8): which float4 d-slice (d = 4*dl .. 4*dl+3)
// 25 iterations x 8 f-rows = F=200 exactly. Loads are 16B/lane, 1KB/wave, coalesced.
__global__ __launch_bounds__(256) void mvke_fused(
    const float* __restrict__ x, const float* __restrict__ tag,
    const float* __restrict__ vk,
    const float* __restrict__ W1, const float* __restrict__ b1,
    const float* __restrict__ g1, const float* __restrict__ be1,
    const float* __restrict__ m1, const float* __restrict__ v1,
    const float* __restrict__ W2, const float* __restrict__ b2,
    const float* __restrict__ g2, const float* __restrict__ be2,
    const float* __restrict__ m2, const float* __restrict__ v2,
    float* __restrict__ out, int nrows)
{
  __shared__ float w1s[NK*ND*NH1];    // 16 KB
  __shared__ float w2s[NK*NH1*NH2];   //  8 KB
  __shared__ float a1s[NK*NH1], c1s[NK*NH1];
  __shared__ float a2s[NK*NH2], c2s[NK*NH2];
  __shared__ float ctx_s[4][NK*ND];   // per-wave pooled context
  __shared__ float h1_s[4][NK*NH1];   // per-wave tower-1 activations

  const int tid = threadIdx.x;
  // ---- block-wide preload of weights + folded BN params ----
  for (int i = tid; i < NK*ND*NH1; i += 256) w1s[i] = W1[i];
  for (int i = tid; i < NK*NH1*NH2; i += 256) w2s[i] = W2[i];
  if (tid < NK*NH1) {
    const float a = g1[tid] * rsqrtf(v1[tid] + BN_EPS);
    a1s[tid] = a;
    c1s[tid] = (b1[tid] - m1[tid]) * a + be1[tid];
  } else if (tid >= 128 && tid < 128 + NK*NH2) {
    const int t = tid - 128;
    const float a = g2[t] * rsqrtf(v2[t] + BN_EPS);
    a2s[t] = a;
    c2s[t] = (b2[t] - m2[t]) * a + be2[t];
  }

  const int wave = tid >> 6;
  const int lane = tid & 63;
  const int fg   = lane >> 3;
  const int dl   = lane & 7;
  const int row  = blockIdx.x * 4 + wave;
  const bool live = (row < nrows);

  // vk transposed into registers: vkt[k][j] = vk[(4*dl+j), k]
  float vkt[NK][4];
  #pragma unroll
  for (int j = 0; j < 4; ++j) {
    const float4 vv = *(const float4*)(vk + (4*dl + j) * NK);
    vkt[0][j] = vv.x; vkt[1][j] = vv.y; vkt[2][j] = vv.z; vkt[3][j] = vv.w;
  }

  const float* xrow = x + (size_t)(live ? row : 0) * (NF*ND);
  const int laneoff = fg*ND + dl*4;

  float cx[NK], cy[NK], cz[NK], cw[NK], ls[NK];
  #pragma unroll
  for (int k = 0; k < NK; ++k) { cx[k]=cy[k]=cz[k]=cw[k]=ls[k]=0.f; }

  // ---- stage 1: single streaming pass, un-normalized online softmax ----
  for (int it = 0; it < NF/8; ++it) {
    const float4 xa = *(const float4*)(xrow + it*(8*ND) + laneoff);
    #pragma unroll
    for (int k = 0; k < NK; ++k) {
      float t = xa.x*vkt[k][0] + xa.y*vkt[k][1] + xa.z*vkt[k][2] + xa.w*vkt[k][3];
      t += __shfl_xor(t, 1);
      t += __shfl_xor(t, 2);
      t += __shfl_xor(t, 4);           // now all 8 dl-lanes of this fg have s_k(f)
      const float p = __expf(t);       // |s| <= ~6 here, exp is fp32-safe
      ls[k] += p;
      cx[k] = fmaf(p, xa.x, cx[k]);
      cy[k] = fmaf(p, xa.y, cy[k]);
      cz[k] = fmaf(p, xa.z, cz[k]);
      cw[k] = fmaf(p, xa.w, cw[k]);
    }
  }

  // combine the 8 f-groups
  #pragma unroll
  for (int k = 0; k < NK; ++k) {
    #pragma unroll
    for (int m = 8; m <= 32; m <<= 1) {
      ls[k] += __shfl_xor(ls[k], m);
      cx[k] += __shfl_xor(cx[k], m);
      cy[k] += __shfl_xor(cy[k], m);
      cz[k] += __shfl_xor(cz[k], m);
      cw[k] += __shfl_xor(cw[k], m);
    }
  }

  const float scale = 0.17677669529663687f;  // 1/sqrt(32)
  if (fg == 0) {
    #pragma unroll
    for (int k = 0; k < NK; ++k) {
      const float inv = scale / ls[k];
      float* p = &ctx_s[wave][k*ND + dl*4];
      p[0] = cx[k]*inv; p[1] = cy[k]*inv; p[2] = cz[k]*inv; p[3] = cw[k]*inv;
    }
  }
  __syncthreads();   // covers weight preload + ctx_s writes

  // ---- stage 2: tower 1 (Dense -> BN -> relu), 128 outputs, 2 per lane ----
  #pragma unroll
  for (int rep = 0; rep < 2; ++rep) {
    const int o = lane + rep*64;
    const int k = o >> 5, h = o & 31;
    const float* wp = &w1s[k*(ND*NH1) + h];
    const float* cp = &ctx_s[wave][k*ND];
    float acc = 0.f;
    #pragma unroll
    for (int d = 0; d < ND; ++d) acc = fmaf(cp[d], wp[d*NH1], acc);
    h1_s[wave][o] = fmaxf(fmaf(acc, a1s[o], c1s[o]), 0.f);
  }
  __syncthreads();

  // ---- stage 3: tower 2 + gate + output, 64 outputs, 1 per lane ----
  {
    const int k3 = lane >> 4, j3 = lane & 15;
    const float* wp = &w2s[k3*(NH1*NH2) + j3];
    const float* hp = &h1_s[wave][k3*NH1];
    float acc = 0.f;
    #pragma unroll
    for (int h = 0; h < NH1; ++h) acc = fmaf(hp[h], wp[h*NH2], acc);
    const int o = k3*NH2 + j3;
    const float h2v = fmaxf(fmaf(acc, a2s[o], c2s[o]), 0.f);

    // gate from tag embedding (redundant per lane; tag row is L1-hot)
    const float* tp = tag + (size_t)(live ? row : 0) * ND;
    float gs0=0.f, gs1=0.f, gs2=0.f, gs3=0.f;
    #pragma unroll
    for (int d = 0; d < ND; ++d) {
      const float t = tp[d];
      const float4 vv = *(const float4*)(vk + d*NK);
      gs0 = fmaf(t, vv.x, gs0);
      gs1 = fmaf(t, vv.y, gs1);
      gs2 = fmaf(t, vv.z, gs2);
      gs3 = fmaf(t, vv.w, gs3);
    }
    gs0 *= scale; gs1 *= scale; gs2 *= scale; gs3 *= scale;
    const float mx = fmaxf(fmaxf(gs0, gs1), fmaxf(gs2, gs3));
    const float e0 = __expf(gs0-mx), e1 = __expf(gs1-mx),
                e2 = __expf(gs2-mx), e3 = __expf(gs3-mx);
    const float esum = e0 + e1 + e2 + e3;
    const float ek = (k3 == 0) ? e0 : (k3 == 1) ? e1 : (k3 == 2) ? e2 : e3;

    float val = (ek / esum) * h2v;
    val += __shfl_xor(val, 16);
    val += __shfl_xor(val, 32);        // sum over the 4 experts
    if (live && lane < NH2) out[(size_t)row*NH2 + lane] = val;
  }
}

extern "C" void kernel_launch(void* const* d_in, const int* in_sizes, int n_in,
                              void* d_out, int out_size, void* d_ws, size_t ws_size,
                              hipStream_t stream) {
  const float* x   = (const float*)d_in[0];
  const float* tag = (const float*)d_in[1];
  const float* vk  = (const float*)d_in[2];
  const float* W1  = (const float*)d_in[3];
  const float* b1  = (const float*)d_in[4];
  const float* g1  = (const float*)d_in[5];
  const float* be1 = (const float*)d_in[6];
  const float* m1  = (const float*)d_in[7];
  const float* v1  = (const float*)d_in[8];
  const float* W2  = (const float*)d_in[9];
  const float* b2  = (const float*)d_in[10];
  const float* g2  = (const float*)d_in[11];
  const float* be2 = (const float*)d_in[12];
  const float* m2  = (const float*)d_in[13];
  const float* v2  = (const float*)d_in[14];
  float* out = (float*)d_out;

  const int nrows = in_sizes[1] / ND;          // B from tag_embedding
  const int nblocks = (nrows + 3) / 4;         // 4 waves/block, 1 row/wave
  mvke_fused<<<nblocks, 256, 0, stream>>>(x, tag, vk, W1, b1, g1, be1, m1, v1,
                                          W2, b2, g2, be2, m2, v2, out, nrows);
}